// Round 10
// baseline (108.144 us; speedup 1.0000x reference)
//
#include <hip/hip_runtime.h>
#include <hip/hip_cooperative_groups.h>

// labels[b,l,c] = argmin_q ( LN(t)[b,l,c] - LN(code_book)[c,q] )
//              = argmax_q code_book[c,q]   (LN monotone; tn constant along q)
// => output is a 256-entry per-c label vector broadcast over (B, L).
//
// v10: cooperative single dispatch = v6's non-redundant dataflow without
// the ~5 µs second launch. Ladder lesson: ANY variant where every block
// reads the full 256 KB codebook costs >=17 µs (v1 gather 17, v7 strided
// 24, v8 butterfly 45, v9 LDS 20) — the cost is redundant cold
// distribution after the poison fill evicts L2/L3. v6 (scan once, 64
// blocks) had ~4 µs of kernel but paid ~5 µs for dispatch #2.
// Here: blocks 0-63 compute labels (one contiguous 1 KB row-load per
// wave + 6-step shfl_xor butterfly under (value desc, index asc) — exact
// first-index tie-break, absmax=0 in v5/v6/v8/v9), write to workspace;
// grid-wide sync; all 256 blocks broadcast-store the 2 MB output.

#define C_DIM 256
#define Q_DIM 256
#define OUT_INT4 (4 * 512 * 256 / 4)   // B*L*C / 4 = 131072 int4 stores
#define NBLOCKS 256

namespace cg = cooperative_groups;

__global__ __launch_bounds__(256) void rpq_coop(const float* __restrict__ cb,
                                                int* __restrict__ lab,
                                                int* __restrict__ out) {
    const int tid  = threadIdx.x;
    const int lane = tid & 63;
    const int wave = tid >> 6;

    // Phase A: blocks 0..63 compute one label per wave (256 rows total).
    if (blockIdx.x < 64) {
        const int row = blockIdx.x * 4 + wave;
        float4 v = *(const float4*)(cb + row * Q_DIM + lane * 4);
        float b  = v.x;
        int  idx = lane * 4;
        if (v.y > b) { b = v.y; idx = lane * 4 + 1; }
        if (v.z > b) { b = v.z; idx = lane * 4 + 2; }
        if (v.w > b) { b = v.w; idx = lane * 4 + 3; }
#pragma unroll
        for (int off = 1; off < 64; off <<= 1) {
            float ob = __shfl_xor(b, off, 64);
            int   oi = __shfl_xor(idx, off, 64);
            if (ob > b || (ob == b && oi < idx)) { b = ob; idx = oi; }
        }
        if (lane == 0) lab[row] = idx;
        __threadfence();   // make label visible device-wide before the barrier
    }

    cg::this_grid().sync();

    // Phase B: all blocks broadcast-store. Thread's int4 payload is
    // invariant across its grid-stride stores: for i = blk*256 + tid +
    // k*65536, (4i) mod 256 == 4*(tid & 63).
    const int4 v = ((const int4*)lab)[tid & 63];
    int4* o4 = (int4*)out;
    for (int i = blockIdx.x * 256 + tid; i < OUT_INT4; i += NBLOCKS * 256) {
        o4[i] = v;
    }
}

extern "C" void kernel_launch(void* const* d_in, const int* in_sizes, int n_in,
                              void* d_out, int out_size, void* d_ws, size_t ws_size,
                              hipStream_t stream) {
    // inputs: 0=input_values (B,L,D) f32, 1=W (Q,D) f32, 2=code_book (C,Q) f32, 3=raw_signal
    const float* code_book = (const float*)d_in[2];
    int* lab = (int*)d_ws;            // 256 ints = 1 KB of workspace
    int* out = (int*)d_out;
    void* args[] = { (void*)&code_book, (void*)&lab, (void*)&out };
    hipLaunchCooperativeKernel((void*)rpq_coop, dim3(NBLOCKS), dim3(256),
                               args, 0, stream);
}

// Round 11
// 76.518 us; speedup vs baseline: 1.4133x; 1.4133x over previous
//
#include <hip/hip_runtime.h>

// labels[b,l,c] = argmin_q ( LN(t)[b,l,c] - LN(code_book)[c,q] )
//              = argmax_q code_book[c,q]   (LN monotone; tn constant along q)
// => output is a 256-entry per-c label vector broadcast over (B, L).
//
// v11: single plain dispatch + manual producer/consumer flags = v6's
// non-redundant dataflow (kernel ~4 µs) without the ~5 µs second launch
// (v6) and without hipLaunchCooperativeKernel (+45 µs launch path, v10).
//  - 256 blocks, 1/CU: all co-resident; producers (blockIdx 0-63) are
//    dispatched first in CP order -> progress guaranteed, no deadlock.
//  - Producers: one contiguous 1 KB row-load per wave + 6-step shfl_xor
//    butterfly under (value desc, index asc) — bit-exact first-index
//    tie-break, absmax=0 in v5/v6/v8/v9/v10. Labels + per-block MAGIC
//    flag via agent-scope release atomics (cross-XCD safe).
//  - Everyone: acquire-spin on the 64 flags (s_sleep backoff), then the
//    proven broadcast store (2 int4 per thread).
// Poison-safety: MAGIC has 4 distinct bytes — no byte-repeat memset can
// forge it. If flags survive between iterations, consumers read the
// previous iteration's labels — identical values (deterministic input).

#define C_DIM 256
#define Q_DIM 256
#define OUT_INT4 (4 * 512 * 256 / 4)   // B*L*C / 4 = 131072 int4 stores
#define NBLOCKS 256
#define MAGIC 0x1B7E59A3

__global__ __launch_bounds__(256) void rpq_spin(const float* __restrict__ cb,
                                                int* __restrict__ ws,
                                                int* __restrict__ out) {
    int* lab  = ws;         // ws[0..255]   : labels
    int* flag = ws + 256;   // ws[256..319] : 64 producer flags
    const int tid  = threadIdx.x;
    const int lane = tid & 63;
    const int wave = tid >> 6;

    // ---- Phase A: blocks 0..63 produce one label per wave (256 rows) ----
    if (blockIdx.x < 64) {
        const int row = blockIdx.x * 4 + wave;
        float4 v = *(const float4*)(cb + row * Q_DIM + lane * 4);
        float b  = v.x;
        int  idx = lane * 4;
        if (v.y > b) { b = v.y; idx = lane * 4 + 1; }
        if (v.z > b) { b = v.z; idx = lane * 4 + 2; }
        if (v.w > b) { b = v.w; idx = lane * 4 + 3; }
#pragma unroll
        for (int off = 1; off < 64; off <<= 1) {
            float ob = __shfl_xor(b, off, 64);
            int   oi = __shfl_xor(idx, off, 64);
            if (ob > b || (ob == b && oi < idx)) { b = ob; idx = oi; }
        }
        if (lane == 0)
            __hip_atomic_store(&lab[row], idx, __ATOMIC_RELAXED,
                               __HIP_MEMORY_SCOPE_AGENT);
        __syncthreads();      // all 4 waves' label stores issued & drained
        if (tid == 0)
            __hip_atomic_store(&flag[blockIdx.x], MAGIC, __ATOMIC_RELEASE,
                               __HIP_MEMORY_SCOPE_AGENT);
    }

    // ---- Wait: all 64 flags == MAGIC (lane l polls flag[l]) ----
    for (;;) {
        int f = __hip_atomic_load(&flag[lane], __ATOMIC_ACQUIRE,
                                  __HIP_MEMORY_SCOPE_AGENT);
        if (__all(f == MAGIC)) break;
        __builtin_amdgcn_s_sleep(16);
    }

    // ---- Phase B: broadcast store. Thread's int4 payload is invariant:
    // for i = blk*256 + tid + k*65536, (4i) mod 256 == 4*(tid & 63). ----
    const int b0 = lane * 4;
    int4 v;
    v.x = __hip_atomic_load(&lab[b0 + 0], __ATOMIC_RELAXED, __HIP_MEMORY_SCOPE_AGENT);
    v.y = __hip_atomic_load(&lab[b0 + 1], __ATOMIC_RELAXED, __HIP_MEMORY_SCOPE_AGENT);
    v.z = __hip_atomic_load(&lab[b0 + 2], __ATOMIC_RELAXED, __HIP_MEMORY_SCOPE_AGENT);
    v.w = __hip_atomic_load(&lab[b0 + 3], __ATOMIC_RELAXED, __HIP_MEMORY_SCOPE_AGENT);
    int4* o4 = (int4*)out;
    for (int i = blockIdx.x * 256 + tid; i < OUT_INT4; i += NBLOCKS * 256) {
        o4[i] = v;
    }
}

extern "C" void kernel_launch(void* const* d_in, const int* in_sizes, int n_in,
                              void* d_out, int out_size, void* d_ws, size_t ws_size,
                              hipStream_t stream) {
    // inputs: 0=input_values (B,L,D) f32, 1=W (Q,D) f32, 2=code_book (C,Q) f32, 3=raw_signal
    const float* code_book = (const float*)d_in[2];
    int* ws  = (int*)d_ws;    // 320 ints = 1.25 KB of workspace
    int* out = (int*)d_out;
    rpq_spin<<<NBLOCKS, 256, 0, stream>>>(code_book, ws, out);
}

// Round 12
// 62.767 us; speedup vs baseline: 1.7229x; 1.2191x over previous
//
#include <hip/hip_runtime.h>

// labels[b,l,c] = argmin_q ( LN(t)[b,l,c] - LN(code_book)[c,q] )
//              = argmax_q LN(code_book)[c,q]        (tn constant along q)
//              = argmax_q code_book[c,q]            (global-scalar LN is monotone)
// => output is a 256-entry per-c label vector broadcast over (B, L).
//
// v12 = v6 verbatim (measured best: 62.6 µs). Two-dispatch pipeline:
//  K1 rpq_labels: 256 waves, one per row. Lane l holds cols 4l..4l+3 via a
//     single coalesced float4 load (64 lanes x 16B = the whole 1 KB row),
//     in-lane merge, then the 6-step shfl_xor butterfly under the total
//     order (value desc, index asc) — associative+commutative, exact
//     first-index tie-break (absmax=0 in v5-v11).
//  K2 rpq_bcast: reads the 1 KB label vector (coalesced int4 per lane),
//     broadcast-stores the 2 MB output with the full chip.
// Session ladder (kernel-time over this structure): redundant per-block
// scan +13..54 µs (v1/v7/v8/v9), coop grid-sync +45 µs (v10), flag-spin
// +26 µs (v11), second dispatch +5 µs (this) — two-dispatch wins.
// Residual budget: ~42 µs poison fill (80% HBM, harness-owned) + ~14 µs
// dispatch/gap overhead + ~5 µs kernels = floor.

#define C_DIM 256
#define Q_DIM 256
#define OUT_INT4 (4 * 512 * 256 / 4)   // B*L*C / 4 = 131072 int4 stores
#define NB_BCAST 256

__global__ __launch_bounds__(256) void rpq_labels(const float* __restrict__ cb,
                                                  int* __restrict__ lab) {
    const int lane = threadIdx.x & 63;
    const int row  = blockIdx.x * 4 + (threadIdx.x >> 6);  // 64 blocks x 4 waves

    float4 v = *(const float4*)(cb + row * Q_DIM + lane * 4);
    // In-lane merge of 4 candidates, ascending index, strict '>' keeps the
    // earliest index on ties.
    float b  = v.x;
    int  idx = lane * 4;
    if (v.y > b) { b = v.y; idx = lane * 4 + 1; }
    if (v.z > b) { b = v.z; idx = lane * 4 + 2; }
    if (v.w > b) { b = v.w; idx = lane * 4 + 3; }
#pragma unroll
    for (int off = 1; off < 64; off <<= 1) {
        float ob = __shfl_xor(b, off, 64);
        int   oi = __shfl_xor(idx, off, 64);
        if (ob > b || (ob == b && oi < idx)) { b = ob; idx = oi; }
    }
    if (lane == 0) lab[row] = idx;
}

__global__ __launch_bounds__(256) void rpq_bcast(const int* __restrict__ lab,
                                                 int* __restrict__ out) {
    const int tid = threadIdx.x;
    // Thread's int4 payload is invariant across its grid-stride stores:
    // for i = blk*256 + tid + k*65536, (4i) mod 256 == 4*(tid & 63),
    // i.e. int4 index (tid & 63) of the label vector.
    const int4 v = ((const int4*)lab)[tid & 63];
    int4* o4 = (int4*)out;
    for (int i = blockIdx.x * 256 + tid; i < OUT_INT4; i += NB_BCAST * 256) {
        o4[i] = v;
    }
}

extern "C" void kernel_launch(void* const* d_in, const int* in_sizes, int n_in,
                              void* d_out, int out_size, void* d_ws, size_t ws_size,
                              hipStream_t stream) {
    // inputs: 0=input_values (B,L,D) f32, 1=W (Q,D) f32, 2=code_book (C,Q) f32, 3=raw_signal
    const float* code_book = (const float*)d_in[2];
    int* lab = (int*)d_ws;            // 256 ints = 1 KB of workspace
    int* out = (int*)d_out;
    rpq_labels<<<64, 256, 0, stream>>>(code_book, lab);
    rpq_bcast<<<NB_BCAST, 256, 0, stream>>>(lab, out);
}